// Round 15
// baseline (136.636 us; speedup 1.0000x reference)
//
#include <hip/hip_runtime.h>
#include <stdint.h>

#define IN_F   4096
#define R_DIM  128
#define OUT_D  4096
#define BSZ    8
#define SEQ    2048
#define M1     (BSZ * SEQ)   /* 16384 */
#define SCALE  2.0f
#define KSPLIT 4

typedef __attribute__((ext_vector_type(8))) short short8;
typedef __attribute__((ext_vector_type(4))) float f32x4;

static __device__ __forceinline__ unsigned short bf16_1(float f) {
    union { __bf16 h; unsigned short u; } v; v.h = (__bf16)f; return v.u;
}
static __device__ __forceinline__ uint32_t pack2(float a, float b) {
    union { __bf16 h[2]; uint32_t u; } v;
    v.h[0] = (__bf16)a; v.h[1] = (__bf16)b;
    return v.u;
}
static __device__ __forceinline__ float bf16_to_f32(unsigned short h) {
    union { uint32_t u; float f; } v; v.u = ((uint32_t)h) << 16;
    return v.f;
}
static __device__ __forceinline__ int swz16(int r) { return ((r >> 2) ^ r) & 15; }

static __device__ __forceinline__ void gll16(const void* g, void* l) {
    __builtin_amdgcn_global_load_lds(
        (const __attribute__((address_space(1))) void*)g,
        (__attribute__((address_space(3))) void*)l, 16, 0, 0);
}

// ================= merged prep: blocks 0-255 Wd->bf16 copy; blocks 256+ g->gT =================
__global__ __launch_bounds__(256) void k_prep(const float* __restrict__ Wd,
                                              unsigned short* __restrict__ wdbf,
                                              const float* __restrict__ g,
                                              unsigned short* __restrict__ gT) {
    __shared__ unsigned short L[128][132];
    const int tid = threadIdx.x;
    if (blockIdx.x < 256) {
        const int gid = blockIdx.x * 256 + tid;
        const float4 v0 = *(const float4*)(Wd + (size_t)gid * 8);
        const float4 v1 = *(const float4*)(Wd + (size_t)gid * 8 + 4);
        uint4 q;
        q.x = pack2(v0.x, v0.y); q.y = pack2(v0.z, v0.w);
        q.z = pack2(v1.x, v1.y); q.w = pack2(v1.z, v1.w);
        *(uint4*)(wdbf + (size_t)gid * 8) = q;
        return;
    }
    const int bb  = blockIdx.x - 256;
    const int b   = bb >> 5;
    const int ot  = bb & 31;
    const int o0  = ot * 128;

#pragma unroll
    for (int rep = 0; rep < 16; ++rep) {
        const int k  = (tid >> 5) + rep * 8;
        const int ob = (tid & 31) * 4;
        float4 v = *(const float4*)(g + ((size_t)b * R_DIM + k) * OUT_D + o0 + ob);
        L[ob + 0][k] = bf16_1(v.x);
        L[ob + 1][k] = bf16_1(v.y);
        L[ob + 2][k] = bf16_1(v.z);
        L[ob + 3][k] = bf16_1(v.w);
    }
    __syncthreads();

    const int o  = tid >> 1;
    const int jh = tid & 1;
    unsigned short* dst = gT + ((size_t)(b * OUT_D + o0 + o)) * R_DIM;
#pragma unroll
    for (int jj = 0; jj < 8; ++jj) {
        const int c = jh * 8 + jj;
        const int slot = c ^ swz16(o);
        uint2 q0 = *(const uint2*)&L[o][c * 8];
        uint2 q1 = *(const uint2*)&L[o][c * 8 + 4];
        uint4 q; q.x = q0.x; q.y = q0.y; q.z = q1.x; q.w = q1.y;
        *(uint4*)(dst + slot * 8) = q;
    }
}

// ================= Pass 1 v5b (structure identical to R13/R14) =================
template <int KSP>
__global__ __launch_bounds__(512, 6) void k_down_v5(const float* __restrict__ x,
                                                    const unsigned short* __restrict__ wdbf,
                                                    unsigned short* __restrict__ part) {
    constexpr int KCHUNK = IN_F / KSP;
    constexpr int NT     = KCHUNK / 64;

    __shared__ unsigned short As[2][64][72];
    __shared__ unsigned short Bs[2][R_DIM * 64];

    const int tid  = threadIdx.x;
    const int lane = tid & 63;
    const int w    = tid >> 6;
    const int wm   = w >> 2;
    const int wn   = w & 3;
    const int mt   = blockIdx.x & 255;
    const int ks   = blockIdx.x >> 8;
    const int row0 = mt * 64;
    const int kbeg = ks * KCHUNK;

    f32x4 acc[2][2];
#pragma unroll
    for (int m = 0; m < 2; ++m)
#pragma unroll
        for (int n = 0; n < 2; ++n)
#pragma unroll
            for (int j = 0; j < 4; ++j) acc[m][n][j] = 0.0f;

    const int arow = tid >> 3;
    const int acol = (tid & 7) << 3;
    const float* asrc = x + (size_t)(row0 + arow) * IN_F + kbeg + acol;

    const int brow = tid >> 3;
    const int bs_s = tid & 7;
    const int bchunk = bs_s ^ (brow & 7);
    const unsigned short* bsrc0 = wdbf + (size_t)brow * IN_F + kbeg + bchunk * 8;
    const unsigned short* bsrc1 = wdbf + (size_t)(brow + 64) * IN_F + kbeg + bchunk * 8;

    float4 ra0, ra1;

    gll16(bsrc0, &Bs[0][tid * 8]);
    gll16(bsrc1, &Bs[0][(tid + 512) * 8]);
    ra0 = *(const float4*)(asrc);
    ra1 = *(const float4*)(asrc + 4);
    {
        uint4 q;
        q.x = pack2(ra0.x, ra0.y); q.y = pack2(ra0.z, ra0.w);
        q.z = pack2(ra1.x, ra1.y); q.w = pack2(ra1.z, ra1.w);
        *(uint4*)&As[0][arow][acol] = q;
    }
    __syncthreads();

    for (int t = 0; t < NT; ++t) {
        const int cur = t & 1, nxt = cur ^ 1;
        if (t + 1 < NT) {
            gll16(bsrc0 + (t + 1) * 64, &Bs[nxt][tid * 8]);
            gll16(bsrc1 + (t + 1) * 64, &Bs[nxt][(tid + 512) * 8]);
            ra0 = *(const float4*)(asrc + (t + 1) * 64);
            ra1 = *(const float4*)(asrc + (t + 1) * 64 + 4);
        }
#pragma unroll
        for (int kk = 0; kk < 64; kk += 32) {
            const int g = lane >> 4;
            const int c = (kk >> 3) + g;
            short8 af[2], bfv[2];
#pragma unroll
            for (int m = 0; m < 2; ++m) {
                const int r = wm * 32 + m * 16 + (lane & 15);
                af[m] = *(const short8*)&As[cur][r][kk + g * 8];
            }
#pragma unroll
            for (int n = 0; n < 2; ++n) {
                const int rB = wn * 32 + n * 16 + (lane & 15);
                const int slot = c ^ (rB & 7);
                bfv[n] = *(const short8*)&Bs[cur][rB * 64 + slot * 8];
            }
#pragma unroll
            for (int m = 0; m < 2; ++m)
#pragma unroll
                for (int n = 0; n < 2; ++n)
                    acc[m][n] = __builtin_amdgcn_mfma_f32_16x16x32_bf16(af[m], bfv[n], acc[m][n], 0, 0, 0);
        }
        if (t + 1 < NT) {
            uint4 q;
            q.x = pack2(ra0.x, ra0.y); q.y = pack2(ra0.z, ra0.w);
            q.z = pack2(ra1.x, ra1.y); q.w = pack2(ra1.z, ra1.w);
            *(uint4*)&As[nxt][arow][acol] = q;
        }
        __syncthreads();
    }

    // epilogue: bounce acc through Bs, then 256B-row coalesced part writes
    {
        unsigned short* Eb = &Bs[0][0];   // 64 x 136 bf16
        const int gq = lane >> 4;
        const int cl = lane & 15;
#pragma unroll
        for (int m = 0; m < 2; ++m)
#pragma unroll
            for (int n = 0; n < 2; ++n)
#pragma unroll
                for (int j = 0; j < 4; ++j) {
                    const int r = wm * 32 + m * 16 + gq * 4 + j;
                    const int c = wn * 32 + n * 16 + cl;
                    Eb[r * 136 + c] = bf16_1(acc[m][n][j]);
                }
    }
    __syncthreads();
    {
        const unsigned short* Eb = &Bs[0][0];
        const int row = tid >> 3;
        const int seg = tid & 7;
        unsigned short* dst = part + (size_t)ks * M1 * R_DIM +
                              (size_t)(row0 + row) * R_DIM + seg * 16;
        const uint4 q0 = *(const uint4*)&Eb[row * 136 + seg * 16];
        const uint4 q1 = *(const uint4*)&Eb[row * 136 + seg * 16 + 8];
        *(uint4*)(dst)     = q0;
        *(uint4*)(dst + 8) = q1;
    }
}

// ---------------- Reduce: down = sum_ks part[ks]; optional chunk-swizzled output ----------------
template <int KS, bool SWZ>
__global__ __launch_bounds__(512) void k_reduce(const unsigned short* __restrict__ part,
                                                unsigned short* __restrict__ down) {
    const size_t chunk = (size_t)blockIdx.x * 512 + threadIdx.x;
    const size_t off = chunk * 8;
    if (off >= (size_t)M1 * R_DIM) return;
    float lo[4] = {0, 0, 0, 0}, hi[4] = {0, 0, 0, 0};
#pragma unroll
    for (int p = 0; p < KS; ++p) {
        uint4 q = *(const uint4*)(part + (size_t)p * M1 * R_DIM + off);
        const uint32_t* a = (const uint32_t*)&q;
#pragma unroll
        for (int i = 0; i < 4; ++i) {
            lo[i] += bf16_to_f32((unsigned short)(a[i] & 0xFFFF));
            hi[i] += bf16_to_f32((unsigned short)(a[i] >> 16));
        }
    }
    uint4 r;
    uint32_t* o = (uint32_t*)&r;
#pragma unroll
    for (int i = 0; i < 4; ++i) o[i] = pack2(lo[i], hi[i]);
    if (SWZ) {
        const int row = (int)(off >> 7);
        const int j   = (int)((off >> 3) & 15);
        const int slot = j ^ swz16(row & 63);
        *(uint4*)(down + ((size_t)row << 7) + slot * 8) = r;
    } else {
        *(uint4*)(down + off) = r;
    }
}

// ---------------- Fallback pass 1 (no split; only if ws tiny) ----------------
#define BM1 64
#define BK1 64
#define PAD 8
static __device__ __forceinline__ void st_bf16x4(unsigned short* p, float4 v) {
    uint2 q; q.x = pack2(v.x, v.y); q.y = pack2(v.z, v.w);
    *(uint2*)p = q;
}

__global__ __launch_bounds__(512) void k_down(const float* __restrict__ x,
                                              const float* __restrict__ Wd,
                                              unsigned short* __restrict__ down) {
    __shared__ unsigned short As[BM1][BK1 + PAD];
    __shared__ unsigned short Bsh[R_DIM][BK1 + PAD];

    const int tid  = threadIdx.x;
    const int lane = tid & 63;
    const int w    = tid >> 6;
    const int wm   = w >> 2;
    const int wn   = w & 3;
    const int row0 = blockIdx.x * BM1;

    f32x4 acc[2][2];
#pragma unroll
    for (int m = 0; m < 2; ++m)
#pragma unroll
        for (int n = 0; n < 2; ++n)
#pragma unroll
            for (int j = 0; j < 4; ++j) acc[m][n][j] = 0.0f;

    const int arow = tid >> 4;
    const int acol = (tid & 15) << 2;
    float4 ra[2], rb[4];

    ra[0] = *(const float4*)(x + (size_t)(row0 + arow) * IN_F + acol);
    ra[1] = *(const float4*)(x + (size_t)(row0 + arow + 32) * IN_F + acol);
#pragma unroll
    for (int i = 0; i < 4; ++i)
        rb[i] = *(const float4*)(Wd + (size_t)(arow + 32 * i) * IN_F + acol);
    st_bf16x4(&As[arow][acol], ra[0]);
    st_bf16x4(&As[arow + 32][acol], ra[1]);
#pragma unroll
    for (int i = 0; i < 4; ++i) st_bf16x4(&Bsh[arow + 32 * i][acol], rb[i]);
    __syncthreads();

    for (int k0 = BK1; k0 <= IN_F; k0 += BK1) {
        const bool more = (k0 < IN_F);
        if (more) {
            ra[0] = *(const float4*)(x + (size_t)(row0 + arow) * IN_F + k0 + acol);
            ra[1] = *(const float4*)(x + (size_t)(row0 + arow + 32) * IN_F + k0 + acol);
#pragma unroll
            for (int i = 0; i < 4; ++i)
                rb[i] = *(const float4*)(Wd + (size_t)(arow + 32 * i) * IN_F + k0 + acol);
        }
#pragma unroll
        for (int kk = 0; kk < BK1; kk += 32) {
            short8 af[2], bfv[2];
#pragma unroll
            for (int m = 0; m < 2; ++m)
                af[m] = *(const short8*)&As[wm * 32 + m * 16 + (lane & 15)][kk + (lane >> 4) * 8];
#pragma unroll
            for (int n = 0; n < 2; ++n)
                bfv[n] = *(const short8*)&Bsh[wn * 32 + n * 16 + (lane & 15)][kk + (lane >> 4) * 8];
#pragma unroll
            for (int m = 0; m < 2; ++m)
#pragma unroll
                for (int n = 0; n < 2; ++n)
                    acc[m][n] = __builtin_amdgcn_mfma_f32_16x16x32_bf16(af[m], bfv[n], acc[m][n], 0, 0, 0);
        }
        __syncthreads();
        if (more) {
            st_bf16x4(&As[arow][acol], ra[0]);
            st_bf16x4(&As[arow + 32][acol], ra[1]);
#pragma unroll
            for (int i = 0; i < 4; ++i) st_bf16x4(&Bsh[arow + 32 * i][acol], rb[i]);
            __syncthreads();
        }
    }

#pragma unroll
    for (int m = 0; m < 2; ++m)
#pragma unroll
        for (int n = 0; n < 2; ++n)
#pragma unroll
            for (int j = 0; j < 4; ++j) {
                int r = row0 + wm * 32 + m * 16 + ((lane >> 4) << 2) + j;
                int c = wn * 32 + n * 16 + (lane & 15);
                down[(size_t)r * R_DIM + c] = bf16_1(acc[m][n][j]);
            }
}

// ---------------- Pass 2 v6 (bit-identical to R14): 32x128 tile, gll staging, 512B-row epilogue ----------------
#define BM2 64
#define BN2 128

__global__ __launch_bounds__(512) void k_out6(const unsigned short* __restrict__ downswz,
                                              const unsigned short* __restrict__ gT,
                                              float* __restrict__ out) {
    __shared__ __align__(16) unsigned char lraw[40960];      // 40 KB -> 4 blocks/CU
    unsigned short* As  = (unsigned short*)lraw;              // 8 KB  [32*128]
    unsigned short* Bsv = (unsigned short*)(lraw + 8192);     // 32 KB [128*128]
    float* Eb = (float*)lraw;                                 // bounce [32][132] f32

    const int tid  = threadIdx.x;
    const int lane = tid & 63;
    const int w    = tid >> 6;
    const int blk  = blockIdx.x;
    const int o_t  = blk & 31;
    const int s_t  = (blk >> 5) & 63;
    const int b    = blk >> 11;
    const int s0   = s_t * 32;
    const int o0   = o_t * BN2;

    const unsigned short* bim = gT + ((size_t)(b * OUT_D + o0)) * R_DIM;
#pragma unroll
    for (int r = 0; r < 4; ++r)
        gll16(bim + (r * 512 + tid) * 8, Bsv + (r * 512 + tid) * 8);
    const unsigned short* aim = downswz + ((size_t)(b * SEQ + s0)) * R_DIM;
    gll16(aim + tid * 8, As + tid * 8);
    __syncthreads();

    f32x4 acc[2];
#pragma unroll
    for (int m = 0; m < 2; ++m)
#pragma unroll
        for (int j = 0; j < 4; ++j) acc[m][j] = 0.0f;

    const int cl = lane & 15;
    const int gq = lane >> 4;
    const int skey = s0 & 63;
#pragma unroll
    for (int kk = 0; kk < R_DIM; kk += 32) {
        const int cbase = (kk >> 3) + gq;
        short8 af[2], bfv;
#pragma unroll
        for (int m = 0; m < 2; ++m) {
            const int r = m * 16 + cl;
            af[m] = *(const short8*)&As[r * R_DIM + ((cbase ^ swz16(skey + r)) * 8)];
        }
        {
            const int o = w * 16 + cl;
            bfv = *(const short8*)&Bsv[o * R_DIM + ((cbase ^ swz16(o)) * 8)];
        }
#pragma unroll
        for (int m = 0; m < 2; ++m)
            acc[m] = __builtin_amdgcn_mfma_f32_16x16x32_bf16(af[m], bfv, acc[m], 0, 0, 0);
    }

    __syncthreads();
#pragma unroll
    for (int m = 0; m < 2; ++m)
#pragma unroll
        for (int j = 0; j < 4; ++j) {
            const int s_l = m * 16 + gq * 4 + j;
            const int o_l = w * 16 + cl;
            Eb[s_l * 132 + o_l] = SCALE * acc[m][j];
        }
    __syncthreads();

    const int l31 = lane & 31;
    const int hi  = lane >> 5;
#pragma unroll
    for (int p = 0; p < 2; ++p) {
        const int row = w * 4 + p * 2 + hi;
        const f32x4 v = *(const f32x4*)&Eb[row * 132 + l31 * 4];
        f32x4* dst = (f32x4*)(out + ((size_t)(b * SEQ + s0 + row)) * OUT_D + o0 + l31 * 4);
        __builtin_nontemporal_store(v, dst);
    }
}

// ---------------- Pass 2 v3 (mid-tier fallback) ----------------
__global__ __launch_bounds__(512) void k_out3(const unsigned short* __restrict__ down,
                                              const float* __restrict__ g,
                                              float* __restrict__ out) {
    __shared__ __align__(16) unsigned char lraw[49152];
    unsigned short* As  = (unsigned short*)lraw;
    unsigned short* Bsv = (unsigned short*)(lraw + 16384);
    float* Eb = (float*)lraw;

    const int tid  = threadIdx.x;
    const int lane = tid & 63;
    const int w    = tid >> 6;
    const int wm   = w >> 2;
    const int wn   = w & 3;
    const int blk  = blockIdx.x;
    const int o_t  = blk & 31;
    const int s_t  = (blk >> 5) & 31;
    const int b    = blk >> 10;
    const int s0   = s_t * BM2;
    const int o0   = o_t * BN2;

    {
        const int rr = tid >> 4;
        const int j  = tid & 15;
        const int sl0 = j ^ swz16(rr);
        const int sl1 = j ^ swz16(rr + 32);
        *(uint4*)&As[rr * R_DIM + sl0 * 8] =
            *(const uint4*)(down + ((size_t)(b * SEQ + s0 + rr) * R_DIM) + j * 8);
        *(uint4*)&As[(rr + 32) * R_DIM + sl1 * 8] =
            *(const uint4*)(down + ((size_t)(b * SEQ + s0 + rr + 32) * R_DIM) + j * 8);
    }
    {
        const int oq  = tid & 31;
        const int kq0 = tid >> 5;
#pragma unroll
        for (int rep = 0; rep < 2; ++rep) {
            const int kq = kq0 + 16 * rep;
            float4 v0 = *(const float4*)(g + ((size_t)b * R_DIM + 4 * kq + 0) * OUT_D + o0 + 4 * oq);
            float4 v1 = *(const float4*)(g + ((size_t)b * R_DIM + 4 * kq + 1) * OUT_D + o0 + 4 * oq);
            float4 v2 = *(const float4*)(g + ((size_t)b * R_DIM + 4 * kq + 2) * OUT_D + o0 + 4 * oq);
            float4 v3 = *(const float4*)(g + ((size_t)b * R_DIM + 4 * kq + 3) * OUT_D + o0 + 4 * oq);
            const float* p0 = (const float*)&v0;
            const float* p1 = (const float*)&v1;
            const float* p2 = (const float*)&v2;
            const float* p3 = (const float*)&v3;
#pragma unroll
            for (int i = 0; i < 4; ++i) {
                const int o = 4 * oq + i;
                uint2 q;
                q.x = pack2(p0[i], p1[i]);
                q.y = pack2(p2[i], p3[i]);
                const int slot = (kq >> 1) ^ swz16(o);
                *(uint2*)&Bsv[o * R_DIM + slot * 8 + (kq & 1) * 4] = q;
            }
        }
    }
    __syncthreads();

    f32x4 acc[2][2];
#pragma unroll
    for (int m = 0; m < 2; ++m)
#pragma unroll
        for (int n = 0; n < 2; ++n)
#pragma unroll
            for (int j = 0; j < 4; ++j) acc[m][n][j] = 0.0f;

    const int cl = lane & 15;
    const int gq = lane >> 4;
#pragma unroll
    for (int kk = 0; kk < R_DIM; kk += 32) {
        const int cbase = (kk >> 3) + gq;
        short8 af[2], bfv[2];
#pragma unroll
        for (int m = 0; m < 2; ++m) {
            const int r = wm * 32 + m * 16 + cl;
            af[m] = *(const short8*)&As[r * R_DIM + (cbase ^ swz16(r)) * 8];
        }
#pragma unroll
        for (int n = 0; n < 2; ++n) {
            const int o = wn * 32 + n * 16 + cl;
            bfv[n] = *(const short8*)&Bsv[o * R_DIM + (cbase ^ swz16(o)) * 8];
        }
#pragma unroll
        for (int m = 0; m < 2; ++m)
#pragma unroll
            for (int n = 0; n < 2; ++n)
                acc[m][n] = __builtin_amdgcn_mfma_f32_16x16x32_bf16(af[m], bfv[n], acc[m][n], 0, 0, 0);
    }

    __syncthreads();
#pragma unroll
    for (int m = 0; m < 2; ++m)
#pragma unroll
        for (int n = 0; n < 2; ++n)
#pragma unroll
            for (int j = 0; j < 4; ++j) {
                const int s_l = wm * 32 + m * 16 + gq * 4 + j;
                const int o_l = wn * 32 + n * 16 + cl;
                Eb[s_l * 132 + o_l] = SCALE * acc[m][n][j];
            }
    __syncthreads();

    const int l31 = lane & 31;
    const int hi  = lane >> 5;
#pragma unroll
    for (int p = 0; p < 4; ++p) {
        const int row = w * 8 + p * 2 + hi;
        const f32x4 v = *(const f32x4*)&Eb[row * 132 + l31 * 4];
        f32x4* dst = (f32x4*)(out + ((size_t)(b * SEQ + s0 + row)) * OUT_D + o0 + l31 * 4);
        __builtin_nontemporal_store(v, dst);
    }
}

extern "C" void kernel_launch(void* const* d_in, const int* in_sizes, int n_in,
                              void* d_out, int out_size, void* d_ws, size_t ws_size,
                              hipStream_t stream) {
    const float* graph_rep = (const float*)d_in[0];
    const float* x         = (const float*)d_in[1];
    const float* Wd        = (const float*)d_in[2];
    float* out             = (float*)d_out;

    const size_t de = (size_t)M1 * R_DIM;                 // 2M elems
    const size_t we = (size_t)R_DIM * IN_F;               // 512K elems
    const size_t ge = (size_t)BSZ * OUT_D * R_DIM;        // 4.2M elems
    const size_t need_full = ((KSPLIT + 1) * de + we + ge) * sizeof(unsigned short);  // ~29 MB
    const size_t need_mid  = ((KSPLIT + 1) * de + we) * sizeof(unsigned short);       // ~21 MB
    const int out_grid3 = BSZ * (SEQ / BM2) * (OUT_D / BN2);
    const int out_grid6 = BSZ * (SEQ / 32) * (OUT_D / BN2);   // 16384

    if (ws_size >= need_full) {
        unsigned short* part = (unsigned short*)d_ws;
        unsigned short* down = part + KSPLIT * de;   // chunk-swizzled image
        unsigned short* wdbf = part + (KSPLIT + 1) * de;
        unsigned short* gT   = wdbf + we;
        k_prep<<<256 + BSZ * 32, 256, 0, stream>>>(Wd, wdbf, graph_rep, gT);
        k_down_v5<KSPLIT><<<256 * KSPLIT, 512, 0, stream>>>(x, wdbf, part);
        k_reduce<KSPLIT, true><<<(int)(de / 8 / 512), 512, 0, stream>>>(part, down);
        k_out6<<<out_grid6, 512, 0, stream>>>(down, gT, out);
    } else if (ws_size >= need_mid) {
        unsigned short* part = (unsigned short*)d_ws;
        unsigned short* down = part + KSPLIT * de;
        unsigned short* wdbf = part + (KSPLIT + 1) * de;
        k_prep<<<256, 256, 0, stream>>>(Wd, wdbf, graph_rep, wdbf);   // only prep_w blocks run
        k_down_v5<KSPLIT><<<256 * KSPLIT, 512, 0, stream>>>(x, wdbf, part);
        k_reduce<KSPLIT, false><<<(int)(de / 8 / 512), 512, 0, stream>>>(part, down);
        k_out3<<<out_grid3, 512, 0, stream>>>(down, graph_rep, out);
    } else {
        unsigned short* down = (unsigned short*)d_ws;
        k_down<<<M1 / BM1, 512, 0, stream>>>(x, Wd, down);
        k_out3<<<out_grid3, 512, 0, stream>>>(down, graph_rep, out);
    }
}

// Round 16
// 132.832 us; speedup vs baseline: 1.0286x; 1.0286x over previous
//
#include <hip/hip_runtime.h>
#include <stdint.h>

#define IN_F   4096
#define R_DIM  128
#define OUT_D  4096
#define BSZ    8
#define SEQ    2048
#define M1     (BSZ * SEQ)   /* 16384 */
#define SCALE  2.0f
#define KSPLIT 8

typedef __attribute__((ext_vector_type(8))) short short8;
typedef __attribute__((ext_vector_type(4))) float f32x4;

static __device__ __forceinline__ unsigned short bf16_1(float f) {
    union { __bf16 h; unsigned short u; } v; v.h = (__bf16)f; return v.u;
}
static __device__ __forceinline__ uint32_t pack2(float a, float b) {
    union { __bf16 h[2]; uint32_t u; } v;
    v.h[0] = (__bf16)a; v.h[1] = (__bf16)b;
    return v.u;
}
static __device__ __forceinline__ float bf16_to_f32(unsigned short h) {
    union { uint32_t u; float f; } v; v.u = ((uint32_t)h) << 16;
    return v.f;
}
static __device__ __forceinline__ int swz16(int r) { return ((r >> 2) ^ r) & 15; }

static __device__ __forceinline__ void gll16(const void* g, void* l) {
    __builtin_amdgcn_global_load_lds(
        (const __attribute__((address_space(1))) void*)g,
        (__attribute__((address_space(3))) void*)l, 16, 0, 0);
}

// ================= merged prep: blocks 0-255 Wd->bf16 copy; blocks 256+ g->gT =================
__global__ __launch_bounds__(256) void k_prep(const float* __restrict__ Wd,
                                              unsigned short* __restrict__ wdbf,
                                              const float* __restrict__ g,
                                              unsigned short* __restrict__ gT) {
    __shared__ unsigned short L[128][132];
    const int tid = threadIdx.x;
    if (blockIdx.x < 256) {
        const int gid = blockIdx.x * 256 + tid;
        const float4 v0 = *(const float4*)(Wd + (size_t)gid * 8);
        const float4 v1 = *(const float4*)(Wd + (size_t)gid * 8 + 4);
        uint4 q;
        q.x = pack2(v0.x, v0.y); q.y = pack2(v0.z, v0.w);
        q.z = pack2(v1.x, v1.y); q.w = pack2(v1.z, v1.w);
        *(uint4*)(wdbf + (size_t)gid * 8) = q;
        return;
    }
    const int bb  = blockIdx.x - 256;
    const int b   = bb >> 5;
    const int ot  = bb & 31;
    const int o0  = ot * 128;

#pragma unroll
    for (int rep = 0; rep < 16; ++rep) {
        const int k  = (tid >> 5) + rep * 8;
        const int ob = (tid & 31) * 4;
        float4 v = *(const float4*)(g + ((size_t)b * R_DIM + k) * OUT_D + o0 + ob);
        L[ob + 0][k] = bf16_1(v.x);
        L[ob + 1][k] = bf16_1(v.y);
        L[ob + 2][k] = bf16_1(v.z);
        L[ob + 3][k] = bf16_1(v.w);
    }
    __syncthreads();

    const int o  = tid >> 1;
    const int jh = tid & 1;
    unsigned short* dst = gT + ((size_t)(b * OUT_D + o0 + o)) * R_DIM;
#pragma unroll
    for (int jj = 0; jj < 8; ++jj) {
        const int c = jh * 8 + jj;
        const int slot = c ^ swz16(o);
        uint2 q0 = *(const uint2*)&L[o][c * 8];
        uint2 q1 = *(const uint2*)&L[o][c * 8 + 4];
        uint4 q; q.x = q0.x; q.y = q0.y; q.z = q1.x; q.w = q1.y;
        *(uint4*)(dst + slot * 8) = q;
    }
}

// ================= Pass 1 v5b (confirmed best: KSPLIT=8) =================
template <int KSP>
__global__ __launch_bounds__(512, 6) void k_down_v5(const float* __restrict__ x,
                                                    const unsigned short* __restrict__ wdbf,
                                                    unsigned short* __restrict__ part) {
    constexpr int KCHUNK = IN_F / KSP;
    constexpr int NT     = KCHUNK / 64;

    __shared__ unsigned short As[2][64][72];
    __shared__ unsigned short Bs[2][R_DIM * 64];

    const int tid  = threadIdx.x;
    const int lane = tid & 63;
    const int w    = tid >> 6;
    const int wm   = w >> 2;
    const int wn   = w & 3;
    const int mt   = blockIdx.x & 255;
    const int ks   = blockIdx.x >> 8;
    const int row0 = mt * 64;
    const int kbeg = ks * KCHUNK;

    f32x4 acc[2][2];
#pragma unroll
    for (int m = 0; m < 2; ++m)
#pragma unroll
        for (int n = 0; n < 2; ++n)
#pragma unroll
            for (int j = 0; j < 4; ++j) acc[m][n][j] = 0.0f;

    const int arow = tid >> 3;
    const int acol = (tid & 7) << 3;
    const float* asrc = x + (size_t)(row0 + arow) * IN_F + kbeg + acol;

    const int brow = tid >> 3;
    const int bs_s = tid & 7;
    const int bchunk = bs_s ^ (brow & 7);
    const unsigned short* bsrc0 = wdbf + (size_t)brow * IN_F + kbeg + bchunk * 8;
    const unsigned short* bsrc1 = wdbf + (size_t)(brow + 64) * IN_F + kbeg + bchunk * 8;

    float4 ra0, ra1;

    gll16(bsrc0, &Bs[0][tid * 8]);
    gll16(bsrc1, &Bs[0][(tid + 512) * 8]);
    ra0 = *(const float4*)(asrc);
    ra1 = *(const float4*)(asrc + 4);
    {
        uint4 q;
        q.x = pack2(ra0.x, ra0.y); q.y = pack2(ra0.z, ra0.w);
        q.z = pack2(ra1.x, ra1.y); q.w = pack2(ra1.z, ra1.w);
        *(uint4*)&As[0][arow][acol] = q;
    }
    __syncthreads();

    for (int t = 0; t < NT; ++t) {
        const int cur = t & 1, nxt = cur ^ 1;
        if (t + 1 < NT) {
            gll16(bsrc0 + (t + 1) * 64, &Bs[nxt][tid * 8]);
            gll16(bsrc1 + (t + 1) * 64, &Bs[nxt][(tid + 512) * 8]);
            ra0 = *(const float4*)(asrc + (t + 1) * 64);
            ra1 = *(const float4*)(asrc + (t + 1) * 64 + 4);
        }
#pragma unroll
        for (int kk = 0; kk < 64; kk += 32) {
            const int g = lane >> 4;
            const int c = (kk >> 3) + g;
            short8 af[2], bfv[2];
#pragma unroll
            for (int m = 0; m < 2; ++m) {
                const int r = wm * 32 + m * 16 + (lane & 15);
                af[m] = *(const short8*)&As[cur][r][kk + g * 8];
            }
#pragma unroll
            for (int n = 0; n < 2; ++n) {
                const int rB = wn * 32 + n * 16 + (lane & 15);
                const int slot = c ^ (rB & 7);
                bfv[n] = *(const short8*)&Bs[cur][rB * 64 + slot * 8];
            }
#pragma unroll
            for (int m = 0; m < 2; ++m)
#pragma unroll
                for (int n = 0; n < 2; ++n)
                    acc[m][n] = __builtin_amdgcn_mfma_f32_16x16x32_bf16(af[m], bfv[n], acc[m][n], 0, 0, 0);
        }
        if (t + 1 < NT) {
            uint4 q;
            q.x = pack2(ra0.x, ra0.y); q.y = pack2(ra0.z, ra0.w);
            q.z = pack2(ra1.x, ra1.y); q.w = pack2(ra1.z, ra1.w);
            *(uint4*)&As[nxt][arow][acol] = q;
        }
        __syncthreads();
    }

    // epilogue: bounce acc through Bs, then 256B-row coalesced part writes
    {
        unsigned short* Eb = &Bs[0][0];   // 64 x 136 bf16
        const int gq = lane >> 4;
        const int cl = lane & 15;
#pragma unroll
        for (int m = 0; m < 2; ++m)
#pragma unroll
            for (int n = 0; n < 2; ++n)
#pragma unroll
                for (int j = 0; j < 4; ++j) {
                    const int r = wm * 32 + m * 16 + gq * 4 + j;
                    const int c = wn * 32 + n * 16 + cl;
                    Eb[r * 136 + c] = bf16_1(acc[m][n][j]);
                }
    }
    __syncthreads();
    {
        const unsigned short* Eb = &Bs[0][0];
        const int row = tid >> 3;
        const int seg = tid & 7;
        unsigned short* dst = part + (size_t)ks * M1 * R_DIM +
                              (size_t)(row0 + row) * R_DIM + seg * 16;
        const uint4 q0 = *(const uint4*)&Eb[row * 136 + seg * 16];
        const uint4 q1 = *(const uint4*)&Eb[row * 136 + seg * 16 + 8];
        *(uint4*)(dst)     = q0;
        *(uint4*)(dst + 8) = q1;
    }
}

// ---------------- Reduce: down = sum_ks part[ks]; optional chunk-swizzled output ----------------
template <int KS, bool SWZ>
__global__ __launch_bounds__(512) void k_reduce(const unsigned short* __restrict__ part,
                                                unsigned short* __restrict__ down) {
    const size_t chunk = (size_t)blockIdx.x * 512 + threadIdx.x;
    const size_t off = chunk * 8;
    if (off >= (size_t)M1 * R_DIM) return;
    float lo[4] = {0, 0, 0, 0}, hi[4] = {0, 0, 0, 0};
#pragma unroll
    for (int p = 0; p < KS; ++p) {
        uint4 q = *(const uint4*)(part + (size_t)p * M1 * R_DIM + off);
        const uint32_t* a = (const uint32_t*)&q;
#pragma unroll
        for (int i = 0; i < 4; ++i) {
            lo[i] += bf16_to_f32((unsigned short)(a[i] & 0xFFFF));
            hi[i] += bf16_to_f32((unsigned short)(a[i] >> 16));
        }
    }
    uint4 r;
    uint32_t* o = (uint32_t*)&r;
#pragma unroll
    for (int i = 0; i < 4; ++i) o[i] = pack2(lo[i], hi[i]);
    if (SWZ) {
        const int row = (int)(off >> 7);
        const int j   = (int)((off >> 3) & 15);
        const int slot = j ^ swz16(row & 63);
        *(uint4*)(down + ((size_t)row << 7) + slot * 8) = r;
    } else {
        *(uint4*)(down + off) = r;
    }
}

// ---------------- Fallback pass 1 (no split; only if ws tiny) ----------------
#define BM1 64
#define BK1 64
#define PAD 8
static __device__ __forceinline__ void st_bf16x4(unsigned short* p, float4 v) {
    uint2 q; q.x = pack2(v.x, v.y); q.y = pack2(v.z, v.w);
    *(uint2*)p = q;
}

__global__ __launch_bounds__(512) void k_down(const float* __restrict__ x,
                                              const float* __restrict__ Wd,
                                              unsigned short* __restrict__ down) {
    __shared__ unsigned short As[BM1][BK1 + PAD];
    __shared__ unsigned short Bsh[R_DIM][BK1 + PAD];

    const int tid  = threadIdx.x;
    const int lane = tid & 63;
    const int w    = tid >> 6;
    const int wm   = w >> 2;
    const int wn   = w & 3;
    const int row0 = blockIdx.x * BM1;

    f32x4 acc[2][2];
#pragma unroll
    for (int m = 0; m < 2; ++m)
#pragma unroll
        for (int n = 0; n < 2; ++n)
#pragma unroll
            for (int j = 0; j < 4; ++j) acc[m][n][j] = 0.0f;

    const int arow = tid >> 4;
    const int acol = (tid & 15) << 2;
    float4 ra[2], rb[4];

    ra[0] = *(const float4*)(x + (size_t)(row0 + arow) * IN_F + acol);
    ra[1] = *(const float4*)(x + (size_t)(row0 + arow + 32) * IN_F + acol);
#pragma unroll
    for (int i = 0; i < 4; ++i)
        rb[i] = *(const float4*)(Wd + (size_t)(arow + 32 * i) * IN_F + acol);
    st_bf16x4(&As[arow][acol], ra[0]);
    st_bf16x4(&As[arow + 32][acol], ra[1]);
#pragma unroll
    for (int i = 0; i < 4; ++i) st_bf16x4(&Bsh[arow + 32 * i][acol], rb[i]);
    __syncthreads();

    for (int k0 = BK1; k0 <= IN_F; k0 += BK1) {
        const bool more = (k0 < IN_F);
        if (more) {
            ra[0] = *(const float4*)(x + (size_t)(row0 + arow) * IN_F + k0 + acol);
            ra[1] = *(const float4*)(x + (size_t)(row0 + arow + 32) * IN_F + k0 + acol);
#pragma unroll
            for (int i = 0; i < 4; ++i)
                rb[i] = *(const float4*)(Wd + (size_t)(arow + 32 * i) * IN_F + k0 + acol);
        }
#pragma unroll
        for (int kk = 0; kk < BK1; kk += 32) {
            short8 af[2], bfv[2];
#pragma unroll
            for (int m = 0; m < 2; ++m)
                af[m] = *(const short8*)&As[wm * 32 + m * 16 + (lane & 15)][kk + (lane >> 4) * 8];
#pragma unroll
            for (int n = 0; n < 2; ++n)
                bfv[n] = *(const short8*)&Bsh[wn * 32 + n * 16 + (lane & 15)][kk + (lane >> 4) * 8];
#pragma unroll
            for (int m = 0; m < 2; ++m)
#pragma unroll
                for (int n = 0; n < 2; ++n)
                    acc[m][n] = __builtin_amdgcn_mfma_f32_16x16x32_bf16(af[m], bfv[n], acc[m][n], 0, 0, 0);
        }
        __syncthreads();
        if (more) {
            st_bf16x4(&As[arow][acol], ra[0]);
            st_bf16x4(&As[arow + 32][acol], ra[1]);
#pragma unroll
            for (int i = 0; i < 4; ++i) st_bf16x4(&Bsh[arow + 32 * i][acol], rb[i]);
            __syncthreads();
        }
    }

#pragma unroll
    for (int m = 0; m < 2; ++m)
#pragma unroll
        for (int n = 0; n < 2; ++n)
#pragma unroll
            for (int j = 0; j < 4; ++j) {
                int r = row0 + wm * 32 + m * 16 + ((lane >> 4) << 2) + j;
                int c = wn * 32 + n * 16 + (lane & 15);
                down[(size_t)r * R_DIM + c] = bf16_1(acc[m][n][j]);
            }
}

// ---------------- Pass 2 v6: 32x128 tile, 40KB LDS -> 4 blocks/CU; gll staging; 512B-row epilogue ----------------
#define BM2 64
#define BN2 128

__global__ __launch_bounds__(512) void k_out6(const unsigned short* __restrict__ downswz,
                                              const unsigned short* __restrict__ gT,
                                              float* __restrict__ out) {
    __shared__ __align__(16) unsigned char lraw[40960];      // 40 KB -> 4 blocks/CU
    unsigned short* As  = (unsigned short*)lraw;              // 8 KB  [32*128]
    unsigned short* Bsv = (unsigned short*)(lraw + 8192);     // 32 KB [128*128]
    float* Eb = (float*)lraw;                                 // bounce [32][132] f32

    const int tid  = threadIdx.x;
    const int lane = tid & 63;
    const int w    = tid >> 6;
    const int blk  = blockIdx.x;
    const int o_t  = blk & 31;
    const int s_t  = (blk >> 5) & 63;
    const int b    = blk >> 11;
    const int s0   = s_t * 32;
    const int o0   = o_t * BN2;

    const unsigned short* bim = gT + ((size_t)(b * OUT_D + o0)) * R_DIM;
#pragma unroll
    for (int r = 0; r < 4; ++r)
        gll16(bim + (r * 512 + tid) * 8, Bsv + (r * 512 + tid) * 8);
    const unsigned short* aim = downswz + ((size_t)(b * SEQ + s0)) * R_DIM;
    gll16(aim + tid * 8, As + tid * 8);
    __syncthreads();

    f32x4 acc[2];
#pragma unroll
    for (int m = 0; m < 2; ++m)
#pragma unroll
        for (int j = 0; j < 4; ++j) acc[m][j] = 0.0f;

    const int cl = lane & 15;
    const int gq = lane >> 4;
    const int skey = s0 & 63;
#pragma unroll
    for (int kk = 0; kk < R_DIM; kk += 32) {
        const int cbase = (kk >> 3) + gq;
        short8 af[2], bfv;
#pragma unroll
        for (int m = 0; m < 2; ++m) {
            const int r = m * 16 + cl;
            af[m] = *(const short8*)&As[r * R_DIM + ((cbase ^ swz16(skey + r)) * 8)];
        }
        {
            const int o = w * 16 + cl;
            bfv = *(const short8*)&Bsv[o * R_DIM + ((cbase ^ swz16(o)) * 8)];
        }
#pragma unroll
        for (int m = 0; m < 2; ++m)
            acc[m] = __builtin_amdgcn_mfma_f32_16x16x32_bf16(af[m], bfv, acc[m], 0, 0, 0);
    }

    __syncthreads();
#pragma unroll
    for (int m = 0; m < 2; ++m)
#pragma unroll
        for (int j = 0; j < 4; ++j) {
            const int s_l = m * 16 + gq * 4 + j;
            const int o_l = w * 16 + cl;
            Eb[s_l * 132 + o_l] = SCALE * acc[m][j];
        }
    __syncthreads();

    const int l31 = lane & 31;
    const int hi  = lane >> 5;
#pragma unroll
    for (int p = 0; p < 2; ++p) {
        const int row = w * 4 + p * 2 + hi;
        const f32x4 v = *(const f32x4*)&Eb[row * 132 + l31 * 4];
        f32x4* dst = (f32x4*)(out + ((size_t)(b * SEQ + s0 + row)) * OUT_D + o0 + l31 * 4);
        __builtin_nontemporal_store(v, dst);
    }
}

// ---------------- Pass 2 v3 (mid-tier fallback) ----------------
__global__ __launch_bounds__(512) void k_out3(const unsigned short* __restrict__ down,
                                              const float* __restrict__ g,
                                              float* __restrict__ out) {
    __shared__ __align__(16) unsigned char lraw[49152];
    unsigned short* As  = (unsigned short*)lraw;
    unsigned short* Bsv = (unsigned short*)(lraw + 16384);
    float* Eb = (float*)lraw;

    const int tid  = threadIdx.x;
    const int lane = tid & 63;
    const int w    = tid >> 6;
    const int wm   = w >> 2;
    const int wn   = w & 3;
    const int blk  = blockIdx.x;
    const int o_t  = blk & 31;
    const int s_t  = (blk >> 5) & 31;
    const int b    = blk >> 10;
    const int s0   = s_t * BM2;
    const int o0   = o_t * BN2;

    {
        const int rr = tid >> 4;
        const int j  = tid & 15;
        const int sl0 = j ^ swz16(rr);
        const int sl1 = j ^ swz16(rr + 32);
        *(uint4*)&As[rr * R_DIM + sl0 * 8] =
            *(const uint4*)(down + ((size_t)(b * SEQ + s0 + rr) * R_DIM) + j * 8);
        *(uint4*)&As[(rr + 32) * R_DIM + sl1 * 8] =
            *(const uint4*)(down + ((size_t)(b * SEQ + s0 + rr + 32) * R_DIM) + j * 8);
    }
    {
        const int oq  = tid & 31;
        const int kq0 = tid >> 5;
#pragma unroll
        for (int rep = 0; rep < 2; ++rep) {
            const int kq = kq0 + 16 * rep;
            float4 v0 = *(const float4*)(g + ((size_t)b * R_DIM + 4 * kq + 0) * OUT_D + o0 + 4 * oq);
            float4 v1 = *(const float4*)(g + ((size_t)b * R_DIM + 4 * kq + 1) * OUT_D + o0 + 4 * oq);
            float4 v2 = *(const float4*)(g + ((size_t)b * R_DIM + 4 * kq + 2) * OUT_D + o0 + 4 * oq);
            float4 v3 = *(const float4*)(g + ((size_t)b * R_DIM + 4 * kq + 3) * OUT_D + o0 + 4 * oq);
            const float* p0 = (const float*)&v0;
            const float* p1 = (const float*)&v1;
            const float* p2 = (const float*)&v2;
            const float* p3 = (const float*)&v3;
#pragma unroll
            for (int i = 0; i < 4; ++i) {
                const int o = 4 * oq + i;
                uint2 q;
                q.x = pack2(p0[i], p1[i]);
                q.y = pack2(p2[i], p3[i]);
                const int slot = (kq >> 1) ^ swz16(o);
                *(uint2*)&Bsv[o * R_DIM + slot * 8 + (kq & 1) * 4] = q;
            }
        }
    }
    __syncthreads();

    f32x4 acc[2][2];
#pragma unroll
    for (int m = 0; m < 2; ++m)
#pragma unroll
        for (int n = 0; n < 2; ++n)
#pragma unroll
            for (int j = 0; j < 4; ++j) acc[m][n][j] = 0.0f;

    const int cl = lane & 15;
    const int gq = lane >> 4;
#pragma unroll
    for (int kk = 0; kk < R_DIM; kk += 32) {
        const int cbase = (kk >> 3) + gq;
        short8 af[2], bfv[2];
#pragma unroll
        for (int m = 0; m < 2; ++m) {
            const int r = wm * 32 + m * 16 + cl;
            af[m] = *(const short8*)&As[r * R_DIM + (cbase ^ swz16(r)) * 8];
        }
#pragma unroll
        for (int n = 0; n < 2; ++n) {
            const int o = wn * 32 + n * 16 + cl;
            bfv[n] = *(const short8*)&Bsv[o * R_DIM + (cbase ^ swz16(o)) * 8];
        }
#pragma unroll
        for (int m = 0; m < 2; ++m)
#pragma unroll
            for (int n = 0; n < 2; ++n)
                acc[m][n] = __builtin_amdgcn_mfma_f32_16x16x32_bf16(af[m], bfv[n], acc[m][n], 0, 0, 0);
    }

    __syncthreads();
#pragma unroll
    for (int m = 0; m < 2; ++m)
#pragma unroll
        for (int n = 0; n < 2; ++n)
#pragma unroll
            for (int j = 0; j < 4; ++j) {
                const int s_l = wm * 32 + m * 16 + gq * 4 + j;
                const int o_l = wn * 32 + n * 16 + cl;
                Eb[s_l * 132 + o_l] = SCALE * acc[m][n][j];
            }
    __syncthreads();

    const int l31 = lane & 31;
    const int hi  = lane >> 5;
#pragma unroll
    for (int p = 0; p < 4; ++p) {
        const int row = w * 8 + p * 2 + hi;
        const f32x4 v = *(const f32x4*)&Eb[row * 132 + l31 * 4];
        f32x4* dst = (f32x4*)(out + ((size_t)(b * SEQ + s0 + row)) * OUT_D + o0 + l31 * 4);
        __builtin_nontemporal_store(v, dst);
    }
}

extern "C" void kernel_launch(void* const* d_in, const int* in_sizes, int n_in,
                              void* d_out, int out_size, void* d_ws, size_t ws_size,
                              hipStream_t stream) {
    const float* graph_rep = (const float*)d_in[0];
    const float* x         = (const float*)d_in[1];
    const float* Wd        = (const float*)d_in[2];
    float* out             = (float*)d_out;

    const size_t de = (size_t)M1 * R_DIM;                 // 2M elems
    const size_t we = (size_t)R_DIM * IN_F;               // 512K elems
    const size_t ge = (size_t)BSZ * OUT_D * R_DIM;        // 4.2M elems
    const size_t need_full = ((KSPLIT + 1) * de + we + ge) * sizeof(unsigned short);   // ~45 MB
    const size_t need_mid  = ((KSPLIT + 1) * de + we) * sizeof(unsigned short);        // ~37 MB
    const int out_grid3 = BSZ * (SEQ / BM2) * (OUT_D / BN2);
    const int out_grid6 = BSZ * (SEQ / 32) * (OUT_D / BN2);   // 16384

    if (ws_size >= need_full) {
        unsigned short* part = (unsigned short*)d_ws;
        unsigned short* down = part + KSPLIT * de;   // chunk-swizzled image
        unsigned short* wdbf = part + (KSPLIT + 1) * de;
        unsigned short* gT   = wdbf + we;
        k_prep<<<256 + BSZ * 32, 256, 0, stream>>>(Wd, wdbf, graph_rep, gT);
        k_down_v5<KSPLIT><<<256 * KSPLIT, 512, 0, stream>>>(x, wdbf, part);
        k_reduce<KSPLIT, true><<<(int)(de / 8 / 512), 512, 0, stream>>>(part, down);
        k_out6<<<out_grid6, 512, 0, stream>>>(down, gT, out);
    } else if (ws_size >= need_mid) {
        unsigned short* part = (unsigned short*)d_ws;
        unsigned short* down = part + KSPLIT * de;
        unsigned short* wdbf = part + (KSPLIT + 1) * de;
        k_prep<<<256, 256, 0, stream>>>(Wd, wdbf, graph_rep, wdbf);   // only prep_w blocks run
        k_down_v5<KSPLIT><<<256 * KSPLIT, 512, 0, stream>>>(x, wdbf, part);
        k_reduce<KSPLIT, false><<<(int)(de / 8 / 512), 512, 0, stream>>>(part, down);
        k_out3<<<out_grid3, 512, 0, stream>>>(down, graph_rep, out);
    } else {
        unsigned short* down = (unsigned short*)d_ws;
        k_down<<<M1 / BM1, 512, 0, stream>>>(x, Wd, down);
        k_out3<<<out_grid3, 512, 0, stream>>>(down, graph_rep, out);
    }
}